// Round 11
// baseline (507.030 us; speedup 1.0000x reference)
//
#include <hip/hip_runtime.h>

// ---------------------------------------------------------------------------
// SABlock round 11: gemm_qkv epilogue coalesced via LDS staging (was ~19.5M
// scalar 2B global stores -> store-bound, MfmaUtil 12%). Batch-aligned
// m-tiling (1152 rows/batch, 36 m-tiles) so tiles never straddle batches
// and all epilogue stores are uint4-aligned. attn ctx' and gemm_out use the
// same tiled row index. Math identical to round 10 (passing, absmax 0.030).
// ---------------------------------------------------------------------------

#define B_  4
#define N_  1025
#define C_  768
#define H_  12
#define D_  64
#define M_TOT (B_ * N_)      // 4100
#define MB_T 1152            // rows per batch, 9*128 (batch-aligned tiling)
#define M_T  (B_ * MB_T)     // 4608 tiled rows
#define MT_TILES 36          // 4608/128
#define KEXP 2304            // 3 * 768
#define NPAD 1088            // 17 * 64

#define OFF_EIND 3148800
#define OFF_EIDX 3465216
#define OFF_FIND 3465628
#define OFF_FIDX 3782044
#define OFF_CLS  3782456

// workspace offsets (floats); high water ~76.3 MB
#define WS_F64   0
#define WS_XS    196608      // ushort[4608*2304]  x' A-pattern; later ctx'
#define WS_QKVB  5505024     // ushort[2304*2304]
#define WS_OUTB  8159232     // ushort[768*2304]
#define WS_QE    9043968     // ushort[4*12*1088*128]
#define WS_KE    12386304
#define WS_VT    15728640

// double-region layout (indices into double*)
#define DQ0 0
#define DMS 3072
#define DLG 39936
#define DMX 89136
#define DZ  89184

// splitter work partition
#define SPLIT_A_ITEMS (M_T * 192)            // 884736
#define SPLIT_B1_ITEMS (2304 * 192)          // 442368
#define SPLIT_B2_ITEMS (768 * 192)           // 147456
#define SPLIT_TOTAL (SPLIT_A_ITEMS + SPLIT_B1_ITEMS + SPLIT_B2_ITEMS)

typedef short s16x8 __attribute__((ext_vector_type(8)));
typedef float f32x4 __attribute__((ext_vector_type(4)));

__device__ inline unsigned short f2bf(float f) {
    unsigned u = __float_as_uint(f);
    u += 0x7FFF + ((u >> 16) & 1);          // RNE to bf16
    return (unsigned short)(u >> 16);
}
__device__ inline float bf2f(unsigned short h) {
    return __uint_as_float(((unsigned)h) << 16);
}

// grouped swizzle: 8-wide m super-rows, n fastest inside a super-row
__device__ inline void gemm_decode(int lid, int NT, int MT, int& m, int& n) {
    int gi = lid / (8 * NT);
    int r  = lid % (8 * NT);
    int base = gi * 8;
    int gsize = (MT - base < 8) ? (MT - base) : 8;
    n = r / gsize;
    m = base + r % gsize;
}

// ---------------------------------------------------------------------------
// Merged splitter: A-pattern for x (batch-tiled rows), B-pattern for weights.
// ---------------------------------------------------------------------------
__global__ __launch_bounds__(256) void split_all_kernel(
    const float* __restrict__ x, const float* __restrict__ w_qkv,
    const float* __restrict__ w_out,
    unsigned short* __restrict__ xs, unsigned short* __restrict__ qkvB,
    unsigned short* __restrict__ outB)
{
    int idx = blockIdx.x * 256 + threadIdx.x;
    if (idx < SPLIT_A_ITEMS) {
        int m = idx / 192, c4 = (idx - m * 192) * 4;
        int bb = m / MB_T, n = m - bb * MB_T;
        ushort4 hi = make_ushort4(0,0,0,0), lo = hi;
        if (n < N_) {
            float4 f = *(const float4*)&x[((size_t)(bb*N_ + n)) * C_ + c4];
            hi.x = f2bf(f.x); hi.y = f2bf(f.y); hi.z = f2bf(f.z); hi.w = f2bf(f.w);
            lo.x = f2bf(f.x - bf2f(hi.x)); lo.y = f2bf(f.y - bf2f(hi.y));
            lo.z = f2bf(f.z - bf2f(hi.z)); lo.w = f2bf(f.w - bf2f(hi.w));
        }
        unsigned short* d = xs + (size_t)m * KEXP + c4;
        *(ushort4*)(d)        = hi;
        *(ushort4*)(d + 768)  = hi;
        *(ushort4*)(d + 1536) = lo;
        return;
    }
    idx -= SPLIT_A_ITEMS;
    const float* src;
    unsigned short* dst;
    if (idx < SPLIT_B1_ITEMS) { src = w_qkv; dst = qkvB; }
    else { idx -= SPLIT_B1_ITEMS; if (idx >= SPLIT_B2_ITEMS) return; src = w_out; dst = outB; }
    int m = idx / 192, c4 = (idx - m * 192) * 4;
    float4 f = *(const float4*)&src[(size_t)m * C_ + c4];
    ushort4 hi, lo;
    hi.x = f2bf(f.x); hi.y = f2bf(f.y); hi.z = f2bf(f.z); hi.w = f2bf(f.w);
    lo.x = f2bf(f.x - bf2f(hi.x)); lo.y = f2bf(f.y - bf2f(hi.y));
    lo.z = f2bf(f.z - bf2f(hi.z)); lo.w = f2bf(f.w - bf2f(hi.w));
    unsigned short* d = dst + (size_t)m * KEXP + c4;
    *(ushort4*)(d)        = hi;
    *(ushort4*)(d + 768)  = lo;
    *(ushort4*)(d + 1536) = hi;
}

// ---------------------------------------------------------------------------
// gemm_qkv: pipelined K-loop + LDS-coalesced epilogue.
// LDS union: staging (As 5120 + Bs 5120 us) vs epilogue tile (<=17408 us).
// ---------------------------------------------------------------------------
__global__ __launch_bounds__(256) void gemm_qkv_kernel(
    const unsigned short* __restrict__ A, const unsigned short* __restrict__ Bm,
    unsigned short* __restrict__ qe, unsigned short* __restrict__ ke,
    unsigned short* __restrict__ vtp)
{
    __shared__ unsigned short LU[17408];
    unsigned short* Asb = LU;            // [128][40]
    unsigned short* Bsb = LU + 5120;     // [128][40]

    int mi, ni;
    gemm_decode(blockIdx.x, 18, MT_TILES, mi, ni);
    const int n0 = ni * 128;
    const int m0 = mi * 128;
    const int t = threadIdx.x;
    const int lane = t & 63, wv = t >> 6;
    const int wr = wv >> 1, wc = wv & 1;
    const int q4 = lane >> 4, r = lane & 15;
    const int srow = t >> 2, scol = (t & 3) * 8;

    f32x4 acc[4][4];
    #pragma unroll
    for (int i = 0; i < 4; i++)
        #pragma unroll
        for (int j = 0; j < 4; j++)
            #pragma unroll
            for (int e = 0; e < 4; e++) acc[i][j][e] = 0.f;

    const unsigned short* a0p = A  + (size_t)(m0 + srow) * KEXP + scol;
    const unsigned short* b0p = Bm + (size_t)(n0 + srow) * KEXP + scol;

    uint4 va0 = *(const uint4*)(a0p);
    uint4 va1 = *(const uint4*)(a0p + (size_t)64 * KEXP);
    uint4 vb0 = *(const uint4*)(b0p);
    uint4 vb1 = *(const uint4*)(b0p + (size_t)64 * KEXP);

    for (int kb = 0; kb < KEXP; kb += 32) {
        __syncthreads();
        *(uint4*)&Asb[srow*40 + scol]        = va0;
        *(uint4*)&Asb[(srow + 64)*40 + scol] = va1;
        *(uint4*)&Bsb[srow*40 + scol]        = vb0;
        *(uint4*)&Bsb[(srow + 64)*40 + scol] = vb1;
        __syncthreads();
        int kn = (kb + 32 < KEXP) ? kb + 32 : 0;   // dummy re-read on last iter
        va0 = *(const uint4*)(a0p + kn);
        va1 = *(const uint4*)(a0p + kn + (size_t)64 * KEXP);
        vb0 = *(const uint4*)(b0p + kn);
        vb1 = *(const uint4*)(b0p + kn + (size_t)64 * KEXP);

        s16x8 af[4], bfr[4];
        #pragma unroll
        for (int i = 0; i < 4; i++) {
            af[i]  = *(const s16x8*)&Asb[(wr*64 + i*16 + r)*40 + q4*8];
            bfr[i] = *(const s16x8*)&Bsb[(wc*64 + i*16 + r)*40 + q4*8];
        }
        #pragma unroll
        for (int i = 0; i < 4; i++)
            #pragma unroll
            for (int j = 0; j < 4; j++)
                acc[i][j] = __builtin_amdgcn_mfma_f32_16x16x32_bf16(af[i], bfr[j], acc[i][j], 0, 0, 0);
    }

    const int sel = n0 / C_;
    const int off = n0 % C_;
    const int h0 = off >> 6;
    const int bb = m0 / MB_T;              // blocks never straddle batches
    const int nbase = m0 - bb * MB_T;
    const float scl = (sel == 0) ? 0.125f : 1.0f;

    if (sel <= 1) {
        unsigned short* dstb = (sel == 0) ? qe : ke;
        // two passes over m-halves; LDS tile 64 x 264 (rows [h0:hi|lo][h1:hi|lo])
        #pragma unroll
        for (int half = 0; half < 2; half++) {
            __syncthreads();
            if (wr == half) {
                #pragma unroll
                for (int i = 0; i < 4; i++)
                    #pragma unroll
                    for (int rr = 0; rr < 4; rr++) {
                        int mll = i*16 + q4*4 + rr;
                        #pragma unroll
                        for (int j = 0; j < 4; j++) {
                            float val = acc[i][j][rr] * scl;
                            unsigned short hi = f2bf(val);
                            unsigned short lo = f2bf(val - bf2f(hi));
                            int hd = wc*128 + j*16 + r;
                            LU[mll*264 + hd]      = hi;
                            LU[mll*264 + hd + 64] = lo;
                        }
                    }
            }
            __syncthreads();
            #pragma unroll
            for (int e = 0; e < 8; e++) {
                int u = t + e*256;            // 0..2047
                int row = u >> 5, wi = u & 31;
                int n = nbase + half*64 + row;
                if (n < N_) {
                    int hp = wi >> 4, seg = wi & 15;
                    unsigned short* dst = dstb +
                        ((size_t)((bb*H_ + h0 + hp))*NPAD + n)*128 + seg*8;
                    *(uint4*)dst = *(const uint4*)&LU[row*264 + wi*8];
                }
            }
        }
    } else {
        // vt: two passes per head (wc half); LDS tile 128 x 136 [plane][token]
        #pragma unroll
        for (int hp = 0; hp < 2; hp++) {
            __syncthreads();
            if (wc == hp) {
                #pragma unroll
                for (int i = 0; i < 4; i++)
                    #pragma unroll
                    for (int rr = 0; rr < 4; rr++) {
                        int ml = wr*64 + i*16 + q4*4 + rr;
                        #pragma unroll
                        for (int j = 0; j < 4; j++) {
                            float val = acc[i][j][rr];
                            unsigned short hi = f2bf(val);
                            unsigned short lo = f2bf(val - bf2f(hi));
                            int d = j*16 + r;
                            LU[d*136 + ml]        = hi;
                            LU[(64 + d)*136 + ml] = lo;
                        }
                    }
            }
            __syncthreads();
            unsigned short* pb = vtp + ((size_t)(bb*H_ + h0 + hp))*128*NPAD;
            #pragma unroll
            for (int e = 0; e < 8; e++) {
                int u = t + e*256;            // 0..2047
                int prow = u >> 4, wi = u & 15;
                int n = nbase + wi*8;         // aligned: nbase % 8 == 0
                if (n < N_) {                 // last uint4 may poke past N_-1 into pad rows: guard start only
                    *(uint4*)(pb + (size_t)prow*NPAD + n) = *(const uint4*)&LU[prow*136 + wi*8];
                }
            }
        }
    }
}

__global__ __launch_bounds__(256) void gemm_out_kernel(
    const unsigned short* __restrict__ A, const unsigned short* __restrict__ Bm,
    const float* __restrict__ bias, float* __restrict__ out)
{
    __shared__ unsigned short As[128][40];
    __shared__ unsigned short Bs[128][40];
    int mi, ni;
    gemm_decode(blockIdx.x, 6, MT_TILES, mi, ni);
    const int n0 = ni * 128;
    const int m0 = mi * 128;
    const int t = threadIdx.x;
    const int lane = t & 63, wv = t >> 6;
    const int wr = wv >> 1, wc = wv & 1;
    const int q4 = lane >> 4, r = lane & 15;
    const int srow = t >> 2, scol = (t & 3) * 8;

    f32x4 acc[4][4];
    #pragma unroll
    for (int i = 0; i < 4; i++)
        #pragma unroll
        for (int j = 0; j < 4; j++)
            #pragma unroll
            for (int e = 0; e < 4; e++) acc[i][j][e] = 0.f;

    const unsigned short* a0p = A  + (size_t)(m0 + srow) * KEXP + scol;
    const unsigned short* b0p = Bm + (size_t)(n0 + srow) * KEXP + scol;

    uint4 va0 = *(const uint4*)(a0p);
    uint4 va1 = *(const uint4*)(a0p + (size_t)64 * KEXP);
    uint4 vb0 = *(const uint4*)(b0p);
    uint4 vb1 = *(const uint4*)(b0p + (size_t)64 * KEXP);

    for (int kb = 0; kb < KEXP; kb += 32) {
        __syncthreads();
        *(uint4*)&As[srow][scol]      = va0;
        *(uint4*)&As[srow + 64][scol] = va1;
        *(uint4*)&Bs[srow][scol]      = vb0;
        *(uint4*)&Bs[srow + 64][scol] = vb1;
        __syncthreads();
        int kn = (kb + 32 < KEXP) ? kb + 32 : 0;
        va0 = *(const uint4*)(a0p + kn);
        va1 = *(const uint4*)(a0p + kn + (size_t)64 * KEXP);
        vb0 = *(const uint4*)(b0p + kn);
        vb1 = *(const uint4*)(b0p + kn + (size_t)64 * KEXP);

        s16x8 af[4], bfr[4];
        #pragma unroll
        for (int i = 0; i < 4; i++) {
            af[i]  = *(const s16x8*)&As[wr*64 + i*16 + r][q4*8];
            bfr[i] = *(const s16x8*)&Bs[wc*64 + i*16 + r][q4*8];
        }
        #pragma unroll
        for (int i = 0; i < 4; i++)
            #pragma unroll
            for (int j = 0; j < 4; j++)
                acc[i][j] = __builtin_amdgcn_mfma_f32_16x16x32_bf16(af[i], bfr[j], acc[i][j], 0, 0, 0);
    }

    const int bb = m0 / MB_T;
    const int nbase = m0 - bb * MB_T;
    #pragma unroll
    for (int i = 0; i < 4; i++) {
        #pragma unroll
        for (int rr = 0; rr < 4; rr++) {
            int n = nbase + wr*64 + i*16 + q4*4 + rr;
            if (n < N_) {
                size_t grow = ((size_t)(bb*N_ + n)) * C_;
                #pragma unroll
                for (int j = 0; j < 4; j++) {
                    int col = n0 + wc*64 + j*16 + r;
                    out[grow + col] = acc[i][j][rr] + bias[col];
                }
            }
        }
    }
}

// ---------------------------------------------------------------------------
// MFMA flash attention (r10 structure, XCD-grouped); ctx' rows batch-tiled.
// ---------------------------------------------------------------------------
__global__ __launch_bounds__(256) void attn_kernel(
    const unsigned short* __restrict__ qe, const unsigned short* __restrict__ ke,
    const unsigned short* __restrict__ vtp, unsigned short* __restrict__ ctxs)
{
    __shared__ unsigned short Qe[64][136];
    __shared__ unsigned short KP[64][136];
    __shared__ unsigned short Vt[64][136];

    const int qt = blockIdx.x / 48;
    const int g  = blockIdx.x - qt * 48;
    const int h = g % 12, b = g / 12;
    const int t = threadIdx.x;
    const int w = t >> 6, lane = t & 63;
    const int quad = lane >> 4, r16 = lane & 15;
    const int q8 = quad * 8;
    const size_t bh = (size_t)(b*H_ + h);

    {
        const unsigned short* src = qe + (bh*NPAD + qt*64 + (t >> 2)) * 128;
        #pragma unroll
        for (int e = 0; e < 4; e++) {
            int c = ((t & 3) + 4*e) * 8;
            *(uint4*)&Qe[t >> 2][c] = *(const uint4*)(src + c);
        }
    }

    int qu;
    {
        int rlo = qt*64, rhi = min(qt*64 + 63, N_ - 1);
        if (rlo == 0) qu = -2;
        else { int b1 = (rlo-1)>>8, b2 = (rhi-1)>>8; qu = (b1==b2) ? b1 : -2; }
    }

    float m_run[4], l_run[4];
    f32x4 ctx[4];
    #pragma unroll
    for (int i = 0; i < 4; i++) {
        m_run[i] = -1e30f; l_run[i] = 0.f;
        #pragma unroll
        for (int e = 0; e < 4; e++) ctx[i][e] = 0.f;
    }

    for (int kt = 0; kt < 17; kt++) {
        if (qu >= 0 && kt > 0) {
            int clo = kt*64, chi = min(kt*64 + 63, N_ - 1);
            int b1 = (clo-1)>>8, b2 = (chi-1)>>8;
            if (b1 == b2 && b1 == qu) continue;
        }

        __syncthreads();
        {
            const unsigned short* ksrc = ke + (bh*NPAD + kt*64 + (t >> 2)) * 128;
            #pragma unroll
            for (int e = 0; e < 4; e++) {
                int c = ((t & 3) + 4*e) * 8;
                *(uint4*)&KP[t >> 2][c] = *(const uint4*)(ksrc + c);
            }
            const int p = t >> 1;
            const unsigned short* vsrc = vtp + (bh*128 + p)*NPAD + kt*64;
            const int vd = p & 63, vseg = (p >> 6) * 64;
            #pragma unroll
            for (int e = 0; e < 4; e++) {
                int c = ((t & 1) + 2*e) * 8;
                *(uint4*)&Vt[vd][vseg + c] = *(const uint4*)(vsrc + c);
            }
        }
        __syncthreads();

        f32x4 st[4];
        #pragma unroll
        for (int j = 0; j < 4; j++)
            #pragma unroll
            for (int e = 0; e < 4; e++) st[j][e] = 0.f;
        {
            const int ar = w*16 + r16;
            s16x8 ah0 = *(const s16x8*)&Qe[ar][q8];
            s16x8 ah1 = *(const s16x8*)&Qe[ar][32 + q8];
            s16x8 al0 = *(const s16x8*)&Qe[ar][64 + q8];
            s16x8 al1 = *(const s16x8*)&Qe[ar][96 + q8];
            #pragma unroll
            for (int j = 0; j < 4; j++) {
                const int br = j*16 + r16;
                s16x8 bh0 = *(const s16x8*)&KP[br][q8];
                s16x8 bh1 = *(const s16x8*)&KP[br][32 + q8];
                s16x8 bl0 = *(const s16x8*)&KP[br][64 + q8];
                s16x8 bl1 = *(const s16x8*)&KP[br][96 + q8];
                st[j] = __builtin_amdgcn_mfma_f32_16x16x32_bf16(ah0, bh0, st[j], 0,0,0);
                st[j] = __builtin_amdgcn_mfma_f32_16x16x32_bf16(ah1, bh1, st[j], 0,0,0);
                st[j] = __builtin_amdgcn_mfma_f32_16x16x32_bf16(ah0, bl0, st[j], 0,0,0);
                st[j] = __builtin_amdgcn_mfma_f32_16x16x32_bf16(ah1, bl1, st[j], 0,0,0);
                st[j] = __builtin_amdgcn_mfma_f32_16x16x32_bf16(al0, bh0, st[j], 0,0,0);
                st[j] = __builtin_amdgcn_mfma_f32_16x16x32_bf16(al1, bh1, st[j], 0,0,0);
            }
        }

        float pv[4][4];
        float alpha[4];
        #pragma unroll
        for (int reg = 0; reg < 4; reg++) {
            int gr = qt*64 + w*16 + quad*4 + reg;
            int qb = (gr >= 1) ? ((gr - 1) >> 8) : -1;
            float mx = -1e30f;
            float vv[4];
            #pragma unroll
            for (int j = 0; j < 4; j++) {
                int gc = kt*64 + j*16 + r16;
                bool ok = (gr < N_) && (gc < N_) &&
                          !((gr >= 1) && (gc >= 1) && (((gc - 1) >> 8) == qb));
                vv[j] = ok ? st[j][reg] : -1e30f;
                mx = fmaxf(mx, vv[j]);
            }
            mx = fmaxf(mx, __shfl_xor(mx, 1));
            mx = fmaxf(mx, __shfl_xor(mx, 2));
            mx = fmaxf(mx, __shfl_xor(mx, 4));
            mx = fmaxf(mx, __shfl_xor(mx, 8));
            float mnew = fmaxf(m_run[reg], mx);
            alpha[reg] = __expf(m_run[reg] - mnew);
            m_run[reg] = mnew;
            float ps = 0.f;
            #pragma unroll
            for (int j = 0; j < 4; j++) {
                float pp = (vv[j] > -1e29f) ? __expf(vv[j] - mnew) : 0.f;
                pv[reg][j] = pp; ps += pp;
            }
            ps += __shfl_xor(ps, 1);
            ps += __shfl_xor(ps, 2);
            ps += __shfl_xor(ps, 4);
            ps += __shfl_xor(ps, 8);
            l_run[reg] = l_run[reg] * alpha[reg] + ps;
        }

        __syncthreads();

        #pragma unroll
        for (int reg = 0; reg < 4; reg++) {
            int lrow = w*16 + quad*4 + reg;
            #pragma unroll
            for (int j = 0; j < 4; j++) {
                float pp = pv[reg][j];
                unsigned short ph = f2bf(pp);
                unsigned short pl = f2bf(pp - bf2f(ph));
                KP[lrow][j*16 + r16]      = ph;
                KP[lrow][64 + j*16 + r16] = pl;
            }
        }

        #pragma unroll
        for (int nj = 0; nj < 4; nj++)
            #pragma unroll
            for (int reg = 0; reg < 4; reg++)
                ctx[nj][reg] *= alpha[reg];

        {
            const int ar = w*16 + r16;
            s16x8 ph0 = *(const s16x8*)&KP[ar][q8];
            s16x8 ph1 = *(const s16x8*)&KP[ar][32 + q8];
            s16x8 pl0 = *(const s16x8*)&KP[ar][64 + q8];
            s16x8 pl1 = *(const s16x8*)&KP[ar][96 + q8];
            #pragma unroll
            for (int nj = 0; nj < 4; nj++) {
                const int br = nj*16 + r16;
                s16x8 vh0 = *(const s16x8*)&Vt[br][q8];
                s16x8 vh1 = *(const s16x8*)&Vt[br][32 + q8];
                s16x8 vl0 = *(const s16x8*)&Vt[br][64 + q8];
                s16x8 vl1 = *(const s16x8*)&Vt[br][96 + q8];
                ctx[nj] = __builtin_amdgcn_mfma_f32_16x16x32_bf16(ph0, vh0, ctx[nj], 0,0,0);
                ctx[nj] = __builtin_amdgcn_mfma_f32_16x16x32_bf16(ph1, vh1, ctx[nj], 0,0,0);
                ctx[nj] = __builtin_amdgcn_mfma_f32_16x16x32_bf16(ph0, vl0, ctx[nj], 0,0,0);
                ctx[nj] = __builtin_amdgcn_mfma_f32_16x16x32_bf16(ph1, vl1, ctx[nj], 0,0,0);
                ctx[nj] = __builtin_amdgcn_mfma_f32_16x16x32_bf16(pl0, vh0, ctx[nj], 0,0,0);
                ctx[nj] = __builtin_amdgcn_mfma_f32_16x16x32_bf16(pl1, vh1, ctx[nj], 0,0,0);
            }
        }
    }

    #pragma unroll
    for (int reg = 0; reg < 4; reg++) {
        int gr = qt*64 + w*16 + quad*4 + reg;
        if (gr < N_) {
            float inv = 1.0f / l_run[reg];
            size_t row = ((size_t)(b*MB_T + gr)) * KEXP;   // batch-tiled row
            #pragma unroll
            for (int nj = 0; nj < 4; nj++) {
                float val = ctx[nj][reg] * inv;
                unsigned short hi = f2bf(val);
                unsigned short lo = f2bf(val - bf2f(hi));
                int c = h*64 + nj*16 + r16;
                ctxs[row + c]        = hi;
                ctxs[row + 768 + c]  = hi;
                ctxs[row + 1536 + c] = lo;
            }
        }
    }
}

// ---------------------------------------------------------------------------
// cls fp64 path (rounds 5/7, passing).
// ---------------------------------------------------------------------------
__global__ __launch_bounds__(256) void cls_q0_kernel(
    const float* __restrict__ x, const float* __restrict__ w_qkv,
    double* __restrict__ dws)
{
    const int t = threadIdx.x;
    const int wg = blockIdx.x * 4 + (t >> 6);
    const int lane = t & 63;
    const int b = wg / 768, rem = wg - b * 768;
    const float* x0 = x + (size_t)b * N_ * C_;
    const float* wr = w_qkv + (size_t)rem * C_;
    double s = 0.0;
    #pragma unroll
    for (int i = 0; i < 12; i++) {
        int c = lane + i*64;
        s += (double)x0[c] * (double)wr[c];
    }
    #pragma unroll
    for (int o = 1; o < 64; o <<= 1) s += __shfl_xor(s, o);
    if (lane == 0) dws[DQ0 + wg] = s * 0.125;
}

__global__ __launch_bounds__(256) void cls_ms_kernel(
    const float* __restrict__ w_qkv, double* __restrict__ dws)
{
    __shared__ double q0s[64];
    const int t = threadIdx.x;
    const int c = blockIdx.x * 256 + t;
    const int h = blockIdx.y, b = blockIdx.z;
    if (t < 64) q0s[t] = dws[DQ0 + (b*H_ + h)*64 + t];
    __syncthreads();
    const float* wk = w_qkv + (size_t)(C_ + h*64) * C_ + c;
    double s = 0.0;
    #pragma unroll 8
    for (int d = 0; d < 64; d++) s += q0s[d] * (double)wk[(size_t)d * C_];
    dws[DMS + ((size_t)(b*H_ + h))*768 + c] = s;
}

__global__ __launch_bounds__(256) void cls_logits_kernel(
    const float* __restrict__ x, double* __restrict__ dws)
{
    __shared__ double xs[768];
    const int j = blockIdx.x, b = blockIdx.y;
    const int t = threadIdx.x;
    const int w = t >> 6, lane = t & 63;
    const float* xr = x + ((size_t)b * N_ + j) * C_;
    for (int c = t; c < C_; c += 256) xs[c] = (double)xr[c];
    __syncthreads();
    for (int hh = 0; hh < 3; hh++) {
        int h = w + hh * 4;
        const double* ms = dws + DMS + ((size_t)(b*H_ + h))*768;
        double s = 0.0;
        #pragma unroll
        for (int i = 0; i < 12; i++) {
            int c = lane + i*64;
            s += xs[c] * ms[c];
        }
        #pragma unroll
        for (int o = 1; o < 64; o <<= 1) s += __shfl_xor(s, o);
        if (lane == 0) dws[DLG + ((size_t)(b*H_ + h))*1025 + j] = s;
    }
}

__global__ __launch_bounds__(256) void cls_reduce_kernel(
    const double* __restrict__ dwsr, double* __restrict__ dws)
{
    __shared__ double red[256];
    const int h = blockIdx.x, b = blockIdx.y;
    const int t = threadIdx.x;
    const double* lg = dwsr + DLG + ((size_t)(b*H_ + h))*1025;
    double mloc = -1e300;
    for (int j = t; j < N_; j += 256) mloc = fmax(mloc, lg[j]);
    red[t] = mloc; __syncthreads();
    for (int o = 128; o > 0; o >>= 1) {
        if (t < o) red[t] = fmax(red[t], red[t+o]);
        __syncthreads();
    }
    double mx = red[0]; __syncthreads();
    double sloc = 0.0;
    for (int j = t; j < N_; j += 256) sloc += exp(lg[j] - mx);
    red[t] = sloc; __syncthreads();
    for (int o = 128; o > 0; o >>= 1) {
        if (t < o) red[t] += red[t+o];
        __syncthreads();
    }
    if (t == 0) {
        dws[DMX + b*H_ + h] = mx;
        dws[DZ  + b*H_ + h] = red[0];
    }
}

__global__ __launch_bounds__(1024) void cls_final_kernel(
    const double* __restrict__ dws, float* __restrict__ out)
{
    __shared__ double mv[1024];
    __shared__ int eidx[104], fidx[104];
    const int b = blockIdx.x;
    const int t = threadIdx.x;

    double s = 0.0;
    #pragma unroll
    for (int h = 0; h < H_; h++) {
        double mx = dws[DMX + b*H_ + h];
        double Z  = dws[DZ  + b*H_ + h];
        double lg = dws[DLG + ((size_t)(b*H_ + h))*1025 + (t + 1)];
        s += exp(lg - mx) / Z;
    }
    s *= (1.0 / 12.0);
    mv[t] = s;
    out[OFF_CLS + (size_t)b*1024 + t] = (float)s;
    __syncthreads();

    int cd = 0, ca = 0;
    const double v = s;
    for (int j = 0; j < 1024; j++) {
        double u = mv[j];
        bool tie = (u == v) && (j < t);
        cd += (u > v) || tie;
        ca += (u < v) || tie;
    }
    if (cd < 103) eidx[cd] = t;
    if (ca < 103) fidx[ca] = t;
    __syncthreads();

    if (t < 103) {
        out[OFF_EIDX + (size_t)b*103 + t] = (float)eidx[t];
        out[OFF_FIDX + (size_t)b*103 + t] = (float)fidx[t];
    }
    for (int u4 = t*4; u4 < 103*768; u4 += 4096) {
        int e = u4 / 768;
        float ev = (float)eidx[e], fv = (float)fidx[e];
        *(float4*)&out[OFF_EIND + (size_t)b*103*768 + u4] = make_float4(ev, ev, ev, ev);
        *(float4*)&out[OFF_FIND + (size_t)b*103*768 + u4] = make_float4(fv, fv, fv, fv);
    }
}

// ---------------------------------------------------------------------------
extern "C" void kernel_launch(void* const* d_in, const int* in_sizes, int n_in,
                              void* d_out, int out_size, void* d_ws, size_t ws_size,
                              hipStream_t stream)
{
    const float* x     = (const float*)d_in[0];
    const float* w_qkv = (const float*)d_in[1];
    const float* w_out = (const float*)d_in[2];
    const float* b_out = (const float*)d_in[3];
    float* out = (float*)d_out;
    float* ws  = (float*)d_ws;

    double* dws = (double*)(ws + WS_F64);
    unsigned short* xs   = (unsigned short*)(ws + WS_XS);   // x'; later ctx'
    unsigned short* qkvB = (unsigned short*)(ws + WS_QKVB);
    unsigned short* outB = (unsigned short*)(ws + WS_OUTB);
    unsigned short* qe   = (unsigned short*)(ws + WS_QE);
    unsigned short* ke   = (unsigned short*)(ws + WS_KE);
    unsigned short* vtp  = (unsigned short*)(ws + WS_VT);

    split_all_kernel<<<(SPLIT_TOTAL + 255)/256, 256, 0, stream>>>(
        x, w_qkv, w_out, xs, qkvB, outB);

    gemm_qkv_kernel<<<MT_TILES * 18, 256, 0, stream>>>(xs, qkvB, qe, ke, vtp);
    attn_kernel<<<816, 256, 0, stream>>>(qe, ke, vtp, xs);

    cls_q0_kernel<<<768, 256, 0, stream>>>(x, w_qkv, dws);
    cls_ms_kernel<<<dim3(3, H_, B_), 256, 0, stream>>>(w_qkv, dws);
    cls_logits_kernel<<<dim3(N_, B_), 256, 0, stream>>>(x, dws);
    cls_reduce_kernel<<<dim3(H_, B_), 256, 0, stream>>>(dws, dws);
    cls_final_kernel<<<B_, 1024, 0, stream>>>(dws, out);

    gemm_out_kernel<<<MT_TILES * 6, 256, 0, stream>>>(xs, outB, b_out, out);
}

// Round 12
// 466.920 us; speedup vs baseline: 1.0859x; 1.0859x over previous
//
#include <hip/hip_runtime.h>

// ---------------------------------------------------------------------------
// SABlock round 12: round-10 base (472 us, passing) + global_load_lds
// width-16 staging in both GEMM kernels (m93->m97 lever: async direct-to-LDS,
// unpadded 64B rows, frag reads hoisted so next-tile loads overlap MFMAs).
// r11's LDS-epilogue experiment reverted (wrong theory: no write
// amplification existed; occupancy loss regressed it).
// ---------------------------------------------------------------------------

#define B_  4
#define N_  1025
#define C_  768
#define H_  12
#define D_  64
#define M_TOT (B_ * N_)      // 4100
#define M_PAD 4224           // 33 * 128
#define KEXP 2304            // 3 * 768
#define NPAD 1088            // 17 * 64

#define OFF_EIND 3148800
#define OFF_EIDX 3465216
#define OFF_FIND 3465628
#define OFF_FIDX 3782044
#define OFF_CLS  3782456

// workspace offsets (floats)
#define WS_F64   0
#define WS_XS    196608      // ushort[4224*2304]  x' A-pattern; later ctx'
#define WS_QKVB  5062656     // ushort[2304*2304]
#define WS_OUTB  7716864     // ushort[768*2304]
#define WS_QE    8601600     // ushort[4*12*1088*128]
#define WS_KE    11943936
#define WS_VT    15286272

// double-region layout (indices into double*)
#define DQ0 0
#define DMS 3072
#define DLG 39936
#define DMX 89136
#define DZ  89184

// splitter work partition
#define SPLIT_A_ITEMS (M_PAD * 192)          // 811008
#define SPLIT_B1_ITEMS (2304 * 192)          // 442368
#define SPLIT_B2_ITEMS (768 * 192)           // 147456
#define SPLIT_TOTAL (SPLIT_A_ITEMS + SPLIT_B1_ITEMS + SPLIT_B2_ITEMS)

typedef short s16x8 __attribute__((ext_vector_type(8)));
typedef float f32x4 __attribute__((ext_vector_type(4)));

__device__ inline unsigned short f2bf(float f) {
    unsigned u = __float_as_uint(f);
    u += 0x7FFF + ((u >> 16) & 1);          // RNE to bf16
    return (unsigned short)(u >> 16);
}
__device__ inline float bf2f(unsigned short h) {
    return __uint_as_float(((unsigned)h) << 16);
}

// async global->LDS, 16 bytes/lane; LDS dest = wave-uniform base + lane*16
__device__ __forceinline__ void gl2lds16(const unsigned short* g, unsigned short* l) {
    __builtin_amdgcn_global_load_lds(
        (const __attribute__((address_space(1))) unsigned int*)g,
        (__attribute__((address_space(3))) unsigned int*)l,
        16, 0, 0);
}

// grouped swizzle: 8-wide m super-rows, n fastest inside a super-row
__device__ inline void gemm_decode(int lid, int NT, int& m, int& n) {
    int gi = lid / (8 * NT);
    int r  = lid % (8 * NT);
    int base = gi * 8;
    int gsize = (33 - base < 8) ? (33 - base) : 8;
    n = r / gsize;
    m = base + r % gsize;
}

// ---------------------------------------------------------------------------
// Merged splitter: A-pattern for x, B-pattern for w_qkv and w_out.
// ---------------------------------------------------------------------------
__global__ __launch_bounds__(256) void split_all_kernel(
    const float* __restrict__ x, const float* __restrict__ w_qkv,
    const float* __restrict__ w_out,
    unsigned short* __restrict__ xs, unsigned short* __restrict__ qkvB,
    unsigned short* __restrict__ outB)
{
    int idx = blockIdx.x * 256 + threadIdx.x;
    if (idx < SPLIT_A_ITEMS) {
        int m = idx / 192, c4 = (idx - m * 192) * 4;
        ushort4 hi = make_ushort4(0,0,0,0), lo = hi;
        if (m < M_TOT) {
            float4 f = *(const float4*)&x[(size_t)m * C_ + c4];
            hi.x = f2bf(f.x); hi.y = f2bf(f.y); hi.z = f2bf(f.z); hi.w = f2bf(f.w);
            lo.x = f2bf(f.x - bf2f(hi.x)); lo.y = f2bf(f.y - bf2f(hi.y));
            lo.z = f2bf(f.z - bf2f(hi.z)); lo.w = f2bf(f.w - bf2f(hi.w));
        }
        unsigned short* d = xs + (size_t)m * KEXP + c4;
        *(ushort4*)(d)        = hi;
        *(ushort4*)(d + 768)  = hi;
        *(ushort4*)(d + 1536) = lo;
        return;
    }
    idx -= SPLIT_A_ITEMS;
    const float* src;
    unsigned short* dst;
    if (idx < SPLIT_B1_ITEMS) { src = w_qkv; dst = qkvB; }
    else { idx -= SPLIT_B1_ITEMS; if (idx >= SPLIT_B2_ITEMS) return; src = w_out; dst = outB; }
    int m = idx / 192, c4 = (idx - m * 192) * 4;
    float4 f = *(const float4*)&src[(size_t)m * C_ + c4];
    ushort4 hi, lo;
    hi.x = f2bf(f.x); hi.y = f2bf(f.y); hi.z = f2bf(f.z); hi.w = f2bf(f.w);
    lo.x = f2bf(f.x - bf2f(hi.x)); lo.y = f2bf(f.y - bf2f(hi.y));
    lo.z = f2bf(f.z - bf2f(hi.z)); lo.w = f2bf(f.w - bf2f(hi.w));
    unsigned short* d = dst + (size_t)m * KEXP + c4;
    *(ushort4*)(d)        = hi;
    *(ushort4*)(d + 768)  = lo;
    *(ushort4*)(d + 1536) = hi;
}

// ---------------------------------------------------------------------------
// gemm_qkv: global_load_lds staging (unpadded 64B rows), grouped swizzle,
// r10 scalar-scatter epilogue to qe/ke/vt.
// ---------------------------------------------------------------------------
__global__ __launch_bounds__(256) void gemm_qkv_kernel(
    const unsigned short* __restrict__ A, const unsigned short* __restrict__ Bm,
    unsigned short* __restrict__ qe, unsigned short* __restrict__ ke,
    unsigned short* __restrict__ vtp)
{
    __shared__ unsigned short As[128][32];
    __shared__ unsigned short Bs[128][32];
    int mi, ni;
    gemm_decode(blockIdx.x, 18, mi, ni);
    const int n0 = ni * 128;
    const int m0 = mi * 128;
    const int t = threadIdx.x;
    const int lane = t & 63, wv = t >> 6;
    const int wr = wv >> 1, wc = wv & 1;
    const int q4 = lane >> 4, r = lane & 15;
    const int lrr = lane >> 2;            // row-within-16 group
    const int lcc = (lane & 3) * 8;       // k-chunk

    f32x4 acc[4][4];
    #pragma unroll
    for (int i = 0; i < 4; i++)
        #pragma unroll
        for (int j = 0; j < 4; j++)
            #pragma unroll
            for (int e = 0; e < 4; e++) acc[i][j][e] = 0.f;

    const unsigned short* gA = A  + (size_t)(m0 + wv*16 + lrr) * KEXP + lcc;
    const unsigned short* gB = Bm + (size_t)(n0 + wv*16 + lrr) * KEXP + lcc;
    unsigned short* lA0 = &As[wv*16][0];
    unsigned short* lA1 = &As[64 + wv*16][0];
    unsigned short* lB0 = &Bs[wv*16][0];
    unsigned short* lB1 = &Bs[64 + wv*16][0];

    // prologue: issue tile kb=0
    gl2lds16(gA, lA0);
    gl2lds16(gA + (size_t)64 * KEXP, lA1);
    gl2lds16(gB, lB0);
    gl2lds16(gB + (size_t)64 * KEXP, lB1);

    for (int kb = 0; kb < KEXP; kb += 32) {
        __syncthreads();   // per-wave vmcnt(0) drain + barrier: tile kb ready
        s16x8 af[4], bfr[4];
        #pragma unroll
        for (int i = 0; i < 4; i++) {
            af[i]  = *(const s16x8*)&As[wr*64 + i*16 + r][q4*8];
            bfr[i] = *(const s16x8*)&Bs[wc*64 + i*16 + r][q4*8];
        }
        __syncthreads();   // all waves' ds_reads done; LDS free to overwrite
        if (kb + 32 < KEXP) {
            gl2lds16(gA + kb + 32, lA0);
            gl2lds16(gA + kb + 32 + (size_t)64 * KEXP, lA1);
            gl2lds16(gB + kb + 32, lB0);
            gl2lds16(gB + kb + 32 + (size_t)64 * KEXP, lB1);
        }
        #pragma unroll
        for (int i = 0; i < 4; i++)
            #pragma unroll
            for (int j = 0; j < 4; j++)
                acc[i][j] = __builtin_amdgcn_mfma_f32_16x16x32_bf16(af[i], bfr[j], acc[i][j], 0, 0, 0);
    }

    const int sel = n0 / C_;
    const int off = n0 % C_;
    const float scl = (sel == 0) ? 0.125f : 1.0f;
    #pragma unroll
    for (int i = 0; i < 4; i++) {
        #pragma unroll
        for (int rr = 0; rr < 4; rr++) {
            int gm = m0 + wr*64 + i*16 + q4*4 + rr;
            if (gm < M_TOT) {
                int bb = gm / N_, n = gm - bb * N_;
                #pragma unroll
                for (int j = 0; j < 4; j++) {
                    int col = off + wc*64 + j*16 + r;
                    int h = col >> 6, d = col & 63;
                    float val = acc[i][j][rr] * scl;
                    unsigned short hi = f2bf(val);
                    unsigned short lo = f2bf(val - bf2f(hi));
                    size_t bh = (size_t)(bb*H_ + h);
                    if (sel <= 1) {
                        unsigned short* dst = (sel == 0 ? qe : ke) + (bh*NPAD + n)*128;
                        dst[d]      = hi;
                        dst[64 + d] = lo;
                    } else {
                        unsigned short* dst = vtp + bh*128*NPAD;
                        dst[(size_t)d*NPAD + n]        = hi;
                        dst[(size_t)(64 + d)*NPAD + n] = lo;
                    }
                }
            }
        }
    }
}

__global__ __launch_bounds__(256) void gemm_out_kernel(
    const unsigned short* __restrict__ A, const unsigned short* __restrict__ Bm,
    const float* __restrict__ bias, float* __restrict__ out)
{
    __shared__ unsigned short As[128][32];
    __shared__ unsigned short Bs[128][32];
    int mi, ni;
    gemm_decode(blockIdx.x, 6, mi, ni);
    const int n0 = ni * 128;
    const int m0 = mi * 128;
    const int t = threadIdx.x;
    const int lane = t & 63, wv = t >> 6;
    const int wr = wv >> 1, wc = wv & 1;
    const int q4 = lane >> 4, r = lane & 15;
    const int lrr = lane >> 2;
    const int lcc = (lane & 3) * 8;

    f32x4 acc[4][4];
    #pragma unroll
    for (int i = 0; i < 4; i++)
        #pragma unroll
        for (int j = 0; j < 4; j++)
            #pragma unroll
            for (int e = 0; e < 4; e++) acc[i][j][e] = 0.f;

    const unsigned short* gA = A  + (size_t)(m0 + wv*16 + lrr) * KEXP + lcc;
    const unsigned short* gB = Bm + (size_t)(n0 + wv*16 + lrr) * KEXP + lcc;
    unsigned short* lA0 = &As[wv*16][0];
    unsigned short* lA1 = &As[64 + wv*16][0];
    unsigned short* lB0 = &Bs[wv*16][0];
    unsigned short* lB1 = &Bs[64 + wv*16][0];

    gl2lds16(gA, lA0);
    gl2lds16(gA + (size_t)64 * KEXP, lA1);
    gl2lds16(gB, lB0);
    gl2lds16(gB + (size_t)64 * KEXP, lB1);

    for (int kb = 0; kb < KEXP; kb += 32) {
        __syncthreads();
        s16x8 af[4], bfr[4];
        #pragma unroll
        for (int i = 0; i < 4; i++) {
            af[i]  = *(const s16x8*)&As[wr*64 + i*16 + r][q4*8];
            bfr[i] = *(const s16x8*)&Bs[wc*64 + i*16 + r][q4*8];
        }
        __syncthreads();
        if (kb + 32 < KEXP) {
            gl2lds16(gA + kb + 32, lA0);
            gl2lds16(gA + kb + 32 + (size_t)64 * KEXP, lA1);
            gl2lds16(gB + kb + 32, lB0);
            gl2lds16(gB + kb + 32 + (size_t)64 * KEXP, lB1);
        }
        #pragma unroll
        for (int i = 0; i < 4; i++)
            #pragma unroll
            for (int j = 0; j < 4; j++)
                acc[i][j] = __builtin_amdgcn_mfma_f32_16x16x32_bf16(af[i], bfr[j], acc[i][j], 0, 0, 0);
    }

    #pragma unroll
    for (int i = 0; i < 4; i++) {
        #pragma unroll
        for (int rr = 0; rr < 4; rr++) {
            int gm = m0 + wr*64 + i*16 + q4*4 + rr;
            if (gm < M_TOT) {
                #pragma unroll
                for (int j = 0; j < 4; j++) {
                    int col = n0 + wc*64 + j*16 + r;
                    out[(size_t)gm * C_ + col] = acc[i][j][rr] + bias[col];
                }
            }
        }
    }
}

// ---------------------------------------------------------------------------
// MFMA flash attention (r10, passing): XCD-grouped 1D grid.
// ---------------------------------------------------------------------------
__global__ __launch_bounds__(256) void attn_kernel(
    const unsigned short* __restrict__ qe, const unsigned short* __restrict__ ke,
    const unsigned short* __restrict__ vtp, unsigned short* __restrict__ ctxs)
{
    __shared__ unsigned short Qe[64][136];
    __shared__ unsigned short KP[64][136];
    __shared__ unsigned short Vt[64][136];

    const int qt = blockIdx.x / 48;
    const int g  = blockIdx.x - qt * 48;
    const int h = g % 12, b = g / 12;
    const int t = threadIdx.x;
    const int w = t >> 6, lane = t & 63;
    const int quad = lane >> 4, r16 = lane & 15;
    const int q8 = quad * 8;
    const size_t bh = (size_t)(b*H_ + h);

    {
        const unsigned short* src = qe + (bh*NPAD + qt*64 + (t >> 2)) * 128;
        #pragma unroll
        for (int e = 0; e < 4; e++) {
            int c = ((t & 3) + 4*e) * 8;
            *(uint4*)&Qe[t >> 2][c] = *(const uint4*)(src + c);
        }
    }

    int qu;
    {
        int rlo = qt*64, rhi = min(qt*64 + 63, N_ - 1);
        if (rlo == 0) qu = -2;
        else { int b1 = (rlo-1)>>8, b2 = (rhi-1)>>8; qu = (b1==b2) ? b1 : -2; }
    }

    float m_run[4], l_run[4];
    f32x4 ctx[4];
    #pragma unroll
    for (int i = 0; i < 4; i++) {
        m_run[i] = -1e30f; l_run[i] = 0.f;
        #pragma unroll
        for (int e = 0; e < 4; e++) ctx[i][e] = 0.f;
    }

    for (int kt = 0; kt < 17; kt++) {
        if (qu >= 0 && kt > 0) {
            int clo = kt*64, chi = min(kt*64 + 63, N_ - 1);
            int b1 = (clo-1)>>8, b2 = (chi-1)>>8;
            if (b1 == b2 && b1 == qu) continue;
        }

        __syncthreads();
        {
            const unsigned short* ksrc = ke + (bh*NPAD + kt*64 + (t >> 2)) * 128;
            #pragma unroll
            for (int e = 0; e < 4; e++) {
                int c = ((t & 3) + 4*e) * 8;
                *(uint4*)&KP[t >> 2][c] = *(const uint4*)(ksrc + c);
            }
            const int p = t >> 1;
            const unsigned short* vsrc = vtp + (bh*128 + p)*NPAD + kt*64;
            const int vd = p & 63, vseg = (p >> 6) * 64;
            #pragma unroll
            for (int e = 0; e < 4; e++) {
                int c = ((t & 1) + 2*e) * 8;
                *(uint4*)&Vt[vd][vseg + c] = *(const uint4*)(vsrc + c);
            }
        }
        __syncthreads();

        f32x4 st[4];
        #pragma unroll
        for (int j = 0; j < 4; j++)
            #pragma unroll
            for (int e = 0; e < 4; e++) st[j][e] = 0.f;
        {
            const int ar = w*16 + r16;
            s16x8 ah0 = *(const s16x8*)&Qe[ar][q8];
            s16x8 ah1 = *(const s16x8*)&Qe[ar][32 + q8];
            s16x8 al0 = *(const s16x8*)&Qe[ar][64 + q8];
            s16x8 al1 = *(const s16x8*)&Qe[ar][96 + q8];
            #pragma unroll
            for (int j = 0; j < 4; j++) {
                const int br = j*16 + r16;
                s16x8 bh0 = *(const s16x8*)&KP[br][q8];
                s16x8 bh1 = *(const s16x8*)&KP[br][32 + q8];
                s16x8 bl0 = *(const s16x8*)&KP[br][64 + q8];
                s16x8 bl1 = *(const s16x8*)&KP[br][96 + q8];
                st[j] = __builtin_amdgcn_mfma_f32_16x16x32_bf16(ah0, bh0, st[j], 0,0,0);
                st[j] = __builtin_amdgcn_mfma_f32_16x16x32_bf16(ah1, bh1, st[j], 0,0,0);
                st[j] = __builtin_amdgcn_mfma_f32_16x16x32_bf16(ah0, bl0, st[j], 0,0,0);
                st[j] = __builtin_amdgcn_mfma_f32_16x16x32_bf16(ah1, bl1, st[j], 0,0,0);
                st[j] = __builtin_amdgcn_mfma_f32_16x16x32_bf16(al0, bh0, st[j], 0,0,0);
                st[j] = __builtin_amdgcn_mfma_f32_16x16x32_bf16(al1, bh1, st[j], 0,0,0);
            }
        }

        float pv[4][4];
        float alpha[4];
        #pragma unroll
        for (int reg = 0; reg < 4; reg++) {
            int gr = qt*64 + w*16 + quad*4 + reg;
            int qb = (gr >= 1) ? ((gr - 1) >> 8) : -1;
            float mx = -1e30f;
            float vv[4];
            #pragma unroll
            for (int j = 0; j < 4; j++) {
                int gc = kt*64 + j*16 + r16;
                bool ok = (gr < N_) && (gc < N_) &&
                          !((gr >= 1) && (gc >= 1) && (((gc - 1) >> 8) == qb));
                vv[j] = ok ? st[j][reg] : -1e30f;
                mx = fmaxf(mx, vv[j]);
            }
            mx = fmaxf(mx, __shfl_xor(mx, 1));
            mx = fmaxf(mx, __shfl_xor(mx, 2));
            mx = fmaxf(mx, __shfl_xor(mx, 4));
            mx = fmaxf(mx, __shfl_xor(mx, 8));
            float mnew = fmaxf(m_run[reg], mx);
            alpha[reg] = __expf(m_run[reg] - mnew);
            m_run[reg] = mnew;
            float ps = 0.f;
            #pragma unroll
            for (int j = 0; j < 4; j++) {
                float pp = (vv[j] > -1e29f) ? __expf(vv[j] - mnew) : 0.f;
                pv[reg][j] = pp; ps += pp;
            }
            ps += __shfl_xor(ps, 1);
            ps += __shfl_xor(ps, 2);
            ps += __shfl_xor(ps, 4);
            ps += __shfl_xor(ps, 8);
            l_run[reg] = l_run[reg] * alpha[reg] + ps;
        }

        __syncthreads();

        #pragma unroll
        for (int reg = 0; reg < 4; reg++) {
            int lrow = w*16 + quad*4 + reg;
            #pragma unroll
            for (int j = 0; j < 4; j++) {
                float pp = pv[reg][j];
                unsigned short ph = f2bf(pp);
                unsigned short pl = f2bf(pp - bf2f(ph));
                KP[lrow][j*16 + r16]      = ph;
                KP[lrow][64 + j*16 + r16] = pl;
            }
        }

        #pragma unroll
        for (int nj = 0; nj < 4; nj++)
            #pragma unroll
            for (int reg = 0; reg < 4; reg++)
                ctx[nj][reg] *= alpha[reg];

        {
            const int ar = w*16 + r16;
            s16x8 ph0 = *(const s16x8*)&KP[ar][q8];
            s16x8 ph1 = *(const s16x8*)&KP[ar][32 + q8];
            s16x8 pl0 = *(const s16x8*)&KP[ar][64 + q8];
            s16x8 pl1 = *(const s16x8*)&KP[ar][96 + q8];
            #pragma unroll
            for (int nj = 0; nj < 4; nj++) {
                const int br = nj*16 + r16;
                s16x8 vh0 = *(const s16x8*)&Vt[br][q8];
                s16x8 vh1 = *(const s16x8*)&Vt[br][32 + q8];
                s16x8 vl0 = *(const s16x8*)&Vt[br][64 + q8];
                s16x8 vl1 = *(const s16x8*)&Vt[br][96 + q8];
                ctx[nj] = __builtin_amdgcn_mfma_f32_16x16x32_bf16(ph0, vh0, ctx[nj], 0,0,0);
                ctx[nj] = __builtin_amdgcn_mfma_f32_16x16x32_bf16(ph1, vh1, ctx[nj], 0,0,0);
                ctx[nj] = __builtin_amdgcn_mfma_f32_16x16x32_bf16(ph0, vl0, ctx[nj], 0,0,0);
                ctx[nj] = __builtin_amdgcn_mfma_f32_16x16x32_bf16(ph1, vl1, ctx[nj], 0,0,0);
                ctx[nj] = __builtin_amdgcn_mfma_f32_16x16x32_bf16(pl0, vh0, ctx[nj], 0,0,0);
                ctx[nj] = __builtin_amdgcn_mfma_f32_16x16x32_bf16(pl1, vh1, ctx[nj], 0,0,0);
            }
        }
    }

    #pragma unroll
    for (int reg = 0; reg < 4; reg++) {
        int gr = qt*64 + w*16 + quad*4 + reg;
        if (gr < N_) {
            float inv = 1.0f / l_run[reg];
            size_t row = (size_t)(b*N_ + gr) * KEXP;
            #pragma unroll
            for (int nj = 0; nj < 4; nj++) {
                float val = ctx[nj][reg] * inv;
                unsigned short hi = f2bf(val);
                unsigned short lo = f2bf(val - bf2f(hi));
                int c = h*64 + nj*16 + r16;
                ctxs[row + c]        = hi;
                ctxs[row + 768 + c]  = hi;
                ctxs[row + 1536 + c] = lo;
            }
        }
    }
}

// ---------------------------------------------------------------------------
// cls fp64 path (rounds 5/7, passing).
// ---------------------------------------------------------------------------
__global__ __launch_bounds__(256) void cls_q0_kernel(
    const float* __restrict__ x, const float* __restrict__ w_qkv,
    double* __restrict__ dws)
{
    const int t = threadIdx.x;
    const int wg = blockIdx.x * 4 + (t >> 6);
    const int lane = t & 63;
    const int b = wg / 768, rem = wg - b * 768;
    const float* x0 = x + (size_t)b * N_ * C_;
    const float* wr = w_qkv + (size_t)rem * C_;
    double s = 0.0;
    #pragma unroll
    for (int i = 0; i < 12; i++) {
        int c = lane + i*64;
        s += (double)x0[c] * (double)wr[c];
    }
    #pragma unroll
    for (int o = 1; o < 64; o <<= 1) s += __shfl_xor(s, o);
    if (lane == 0) dws[DQ0 + wg] = s * 0.125;
}

__global__ __launch_bounds__(256) void cls_ms_kernel(
    const float* __restrict__ w_qkv, double* __restrict__ dws)
{
    __shared__ double q0s[64];
    const int t = threadIdx.x;
    const int c = blockIdx.x * 256 + t;
    const int h = blockIdx.y, b = blockIdx.z;
    if (t < 64) q0s[t] = dws[DQ0 + (b*H_ + h)*64 + t];
    __syncthreads();
    const float* wk = w_qkv + (size_t)(C_ + h*64) * C_ + c;
    double s = 0.0;
    #pragma unroll 8
    for (int d = 0; d < 64; d++) s += q0s[d] * (double)wk[(size_t)d * C_];
    dws[DMS + ((size_t)(b*H_ + h))*768 + c] = s;
}

__global__ __launch_bounds__(256) void cls_logits_kernel(
    const float* __restrict__ x, double* __restrict__ dws)
{
    __shared__ double xs[768];
    const int j = blockIdx.x, b = blockIdx.y;
    const int t = threadIdx.x;
    const int w = t >> 6, lane = t & 63;
    const float* xr = x + ((size_t)b * N_ + j) * C_;
    for (int c = t; c < C_; c += 256) xs[c] = (double)xr[c];
    __syncthreads();
    for (int hh = 0; hh < 3; hh++) {
        int h = w + hh * 4;
        const double* ms = dws + DMS + ((size_t)(b*H_ + h))*768;
        double s = 0.0;
        #pragma unroll
        for (int i = 0; i < 12; i++) {
            int c = lane + i*64;
            s += xs[c] * ms[c];
        }
        #pragma unroll
        for (int o = 1; o < 64; o <<= 1) s += __shfl_xor(s, o);
        if (lane == 0) dws[DLG + ((size_t)(b*H_ + h))*1025 + j] = s;
    }
}

__global__ __launch_bounds__(256) void cls_reduce_kernel(
    const double* __restrict__ dwsr, double* __restrict__ dws)
{
    __shared__ double red[256];
    const int h = blockIdx.x, b = blockIdx.y;
    const int t = threadIdx.x;
    const double* lg = dwsr + DLG + ((size_t)(b*H_ + h))*1025;
    double mloc = -1e300;
    for (int j = t; j < N_; j += 256) mloc = fmax(mloc, lg[j]);
    red[t] = mloc; __syncthreads();
    for (int o = 128; o > 0; o >>= 1) {
        if (t < o) red[t] = fmax(red[t], red[t+o]);
        __syncthreads();
    }
    double mx = red[0]; __syncthreads();
    double sloc = 0.0;
    for (int j = t; j < N_; j += 256) sloc += exp(lg[j] - mx);
    red[t] = sloc; __syncthreads();
    for (int o = 128; o > 0; o >>= 1) {
        if (t < o) red[t] += red[t+o];
        __syncthreads();
    }
    if (t == 0) {
        dws[DMX + b*H_ + h] = mx;
        dws[DZ  + b*H_ + h] = red[0];
    }
}

__global__ __launch_bounds__(1024) void cls_final_kernel(
    const double* __restrict__ dws, float* __restrict__ out)
{
    __shared__ double mv[1024];
    __shared__ int eidx[104], fidx[104];
    const int b = blockIdx.x;
    const int t = threadIdx.x;

    double s = 0.0;
    #pragma unroll
    for (int h = 0; h < H_; h++) {
        double mx = dws[DMX + b*H_ + h];
        double Z  = dws[DZ  + b*H_ + h];
        double lg = dws[DLG + ((size_t)(b*H_ + h))*1025 + (t + 1)];
        s += exp(lg - mx) / Z;
    }
    s *= (1.0 / 12.0);
    mv[t] = s;
    out[OFF_CLS + (size_t)b*1024 + t] = (float)s;
    __syncthreads();

    int cd = 0, ca = 0;
    const double v = s;
    for (int j = 0; j < 1024; j++) {
        double u = mv[j];
        bool tie = (u == v) && (j < t);
        cd += (u > v) || tie;
        ca += (u < v) || tie;
    }
    if (cd < 103) eidx[cd] = t;
    if (ca < 103) fidx[ca] = t;
    __syncthreads();

    if (t < 103) {
        out[OFF_EIDX + (size_t)b*103 + t] = (float)eidx[t];
        out[OFF_FIDX + (size_t)b*103 + t] = (float)fidx[t];
    }
    for (int u4 = t*4; u4 < 103*768; u4 += 4096) {
        int e = u4 / 768;
        float ev = (float)eidx[e], fv = (float)fidx[e];
        *(float4*)&out[OFF_EIND + (size_t)b*103*768 + u4] = make_float4(ev, ev, ev, ev);
        *(float4*)&out[OFF_FIND + (size_t)b*103*768 + u4] = make_float4(fv, fv, fv, fv);
    }
}

// ---------------------------------------------------------------------------
extern "C" void kernel_launch(void* const* d_in, const int* in_sizes, int n_in,
                              void* d_out, int out_size, void* d_ws, size_t ws_size,
                              hipStream_t stream)
{
    const float* x     = (const float*)d_in[0];
    const float* w_qkv = (const float*)d_in[1];
    const float* w_out = (const float*)d_in[2];
    const float* b_out = (const float*)d_in[3];
    float* out = (float*)d_out;
    float* ws  = (float*)d_ws;

    double* dws = (double*)(ws + WS_F64);
    unsigned short* xs   = (unsigned short*)(ws + WS_XS);   // x'; later ctx'
    unsigned short* qkvB = (unsigned short*)(ws + WS_QKVB);
    unsigned short* outB = (unsigned short*)(ws + WS_OUTB);
    unsigned short* qe   = (unsigned short*)(ws + WS_QE);
    unsigned short* ke   = (unsigned short*)(ws + WS_KE);
    unsigned short* vtp  = (unsigned short*)(ws + WS_VT);

    split_all_kernel<<<(SPLIT_TOTAL + 255)/256, 256, 0, stream>>>(
        x, w_qkv, w_out, xs, qkvB, outB);

    gemm_qkv_kernel<<<594, 256, 0, stream>>>(xs, qkvB, qe, ke, vtp);
    attn_kernel<<<816, 256, 0, stream>>>(qe, ke, vtp, xs);

    cls_q0_kernel<<<768, 256, 0, stream>>>(x, w_qkv, dws);
    cls_ms_kernel<<<dim3(3, H_, B_), 256, 0, stream>>>(w_qkv, dws);
    cls_logits_kernel<<<dim3(N_, B_), 256, 0, stream>>>(x, dws);
    cls_reduce_kernel<<<dim3(H_, B_), 256, 0, stream>>>(dws, dws);
    cls_final_kernel<<<B_, 1024, 0, stream>>>(dws, out);

    gemm_out_kernel<<<198, 256, 0, stream>>>(xs, outB, b_out, out);
}